// Round 6
// baseline (3861.587 us; speedup 1.0000x reference)
//
#include <hip/hip_runtime.h>
#include <cstdint>

typedef __attribute__((ext_vector_type(8))) short short8;
typedef __attribute__((ext_vector_type(4))) float f32x4;
typedef unsigned short u16;

#define HD 1024      // hidden
#define BSZ 512      // batch
#define NL 2
#define TSTEPS 32
#define BM 64
#define BN 128
#define BK 64

__device__ __forceinline__ u16 f2bf(float x) {
  union { float f; uint32_t u; } v; v.f = x;
  uint32_t r = v.u + 0x7FFFu + ((v.u >> 16) & 1u);   // round-to-nearest-even
  return (u16)(r >> 16);
}
__device__ __forceinline__ float sigm(float x) { return 1.f / (1.f + __expf(-x)); }
__device__ __forceinline__ float tanhfast(float x) { return 1.f - 2.f / (__expf(2.f * x) + 1.f); }

// ---- pack W2[l][n'][k] bf16, n' gate-interleaved: n' = (j/16)*64 + gate*16 + (j%16)
__global__ void pack_w2(const float* __restrict__ Wih, const float* __restrict__ Whh,
                        u16* __restrict__ W2) {
  int idx = blockIdx.x * 256 + threadIdx.x;
  int l   = idx >> 20;
  int rem = idx & 0xFFFFF;
  int np  = rem >> 8;
  int k   = (rem & 255) << 3;
  int gate = (np >> 4) & 3;
  int j    = ((np >> 6) << 4) | (np & 15);
  int n    = (gate << 10) | j;
  const float* src = (k < HD) ? (Wih + ((size_t)(l * 4096 + n) << 10) + k)
                              : (Whh + ((size_t)(l * 4096 + n) << 10) + (k - HD));
  float4 a = reinterpret_cast<const float4*>(src)[0];
  float4 b = reinterpret_cast<const float4*>(src)[1];
  union { u16 s[8]; short8 v; } o;
  o.s[0]=f2bf(a.x); o.s[1]=f2bf(a.y); o.s[2]=f2bf(a.z); o.s[3]=f2bf(a.w);
  o.s[4]=f2bf(b.x); o.s[5]=f2bf(b.y); o.s[6]=f2bf(b.z); o.s[7]=f2bf(b.w);
  *reinterpret_cast<short8*>(W2 + (((size_t)l * 4096 + np) << 11) + k) = o.v;
}

// ---- to_h_W fp32 -> bf16, [2048][1024]
__global__ void pack_thw(const float* __restrict__ thw, u16* __restrict__ dst) {
  int idx = blockIdx.x * 256 + threadIdx.x;
  size_t off = (size_t)idx << 3;
  float4 a = reinterpret_cast<const float4*>(thw + off)[0];
  float4 b = reinterpret_cast<const float4*>(thw + off)[1];
  union { u16 s[8]; short8 v; } o;
  o.s[0]=f2bf(a.x); o.s[1]=f2bf(a.y); o.s[2]=f2bf(a.z); o.s[3]=f2bf(a.w);
  o.s[4]=f2bf(b.x); o.s[5]=f2bf(b.y); o.s[6]=f2bf(b.z); o.s[7]=f2bf(b.w);
  *reinterpret_cast<short8*>(dst + off) = o.v;
}

// ---- z->bf16 | x0 broadcast | bias2 permuted | zero flags
__global__ void pack_small(const float* __restrict__ z, const float* __restrict__ emb,
                           const float* __restrict__ bih, const float* __restrict__ bhh,
                           u16* __restrict__ zb, u16* __restrict__ xb,
                           float* __restrict__ bias2, int* __restrict__ flags) {
  int idx = blockIdx.x * 256 + threadIdx.x;        // 139776 total
  if (idx < 65536) {
    size_t off = (size_t)idx << 3;
    float4 a = reinterpret_cast<const float4*>(z + off)[0];
    float4 b = reinterpret_cast<const float4*>(z + off)[1];
    union { u16 s[8]; short8 v; } o;
    o.s[0]=f2bf(a.x); o.s[1]=f2bf(a.y); o.s[2]=f2bf(a.z); o.s[3]=f2bf(a.w);
    o.s[4]=f2bf(b.x); o.s[5]=f2bf(b.y); o.s[6]=f2bf(b.z); o.s[7]=f2bf(b.w);
    *reinterpret_cast<short8*>(zb + off) = o.v;
  } else if (idx < 131072) {
    size_t off = (size_t)(idx - 65536) << 3;
    int k = (int)(off & 1023);
    float4 a = reinterpret_cast<const float4*>(emb + k)[0];
    float4 b = reinterpret_cast<const float4*>(emb + k)[1];
    union { u16 s[8]; short8 v; } o;
    o.s[0]=f2bf(a.x); o.s[1]=f2bf(a.y); o.s[2]=f2bf(a.z); o.s[3]=f2bf(a.w);
    o.s[4]=f2bf(b.x); o.s[5]=f2bf(b.y); o.s[6]=f2bf(b.z); o.s[7]=f2bf(b.w);
    *reinterpret_cast<short8*>(xb + off) = o.v;
  } else if (idx < 139264) {
    int q = idx - 131072;
    int l = q >> 12, np = q & 4095;
    int gate = (np >> 4) & 3;
    int j    = ((np >> 6) << 4) | (np & 15);
    int n    = (gate << 10) | j;
    bias2[(l << 12) + np] = bih[(l << 12) + n] + bhh[(l << 12) + n];
  } else if (idx < 139776) {
    flags[idx - 139264] = 0;                       // 512 step flags
  }
}

// ---- device-scope semaphores (cross-XCD safe: release/acquire at AGENT scope)
__device__ __forceinline__ void post_flag(int* f, int tid) {
  __threadfence();                                 // each thread's h-writes ordered
  __syncthreads();                                 // whole block done writing
  if (tid == 0) __hip_atomic_fetch_add(f, 1, __ATOMIC_RELEASE, __HIP_MEMORY_SCOPE_AGENT);
}
__device__ __forceinline__ void wait_flag(int* f, int target, int tid) {
  if (tid == 0) {
    while (__hip_atomic_load(f, __ATOMIC_ACQUIRE, __HIP_MEMORY_SCOPE_AGENT) < target)
      __builtin_amdgcn_s_sleep(2);
  }
  __syncthreads();
  __builtin_amdgcn_sched_barrier(0);               // no loads hoisted above the wait
}

// ---- pipelined 64x128 GEMM tile: acc += A[m0..+64, 0..K) @ Wb[0..128, 0..K)^T
// A split at col 1024: A0 then A1 (each row-stride 1024). Wb row-stride K.
// 3-buffer LDS, counted vmcnt (6 loads/thread/stage -> 12/6/0), XOR chunk swizzle.
template<int K>
__device__ __forceinline__ void gemm_tile(
    u16* __restrict__ smem, const u16* __restrict__ A0, const u16* __restrict__ A1,
    const u16* __restrict__ Wb, int m0, int tid, int wr, int wc, int lr, int lk,
    f32x4 (&acc)[2][4])
{
  constexpr int NT = K / BK;
  #pragma unroll
  for (int a = 0; a < 2; ++a)
    #pragma unroll
    for (int b = 0; b < 4; ++b) acc[a][b] = (f32x4){0.f, 0.f, 0.f, 0.f};

  auto stage = [&](int buf, int kt) {
    const int k0 = kt * BK;
    u16* Ad = smem + buf * 12288;
    u16* Bd = Ad + 4096;
    const u16* Aptr; int kk;
    if (k0 < 1024) { Aptr = A0; kk = k0; } else { Aptr = A1; kk = k0 - 1024; }
    #pragma unroll
    for (int i = 0; i < 2; ++i) {                  // A: 64 rows x 8 chunks(16B)
      int d = i * 256 + tid;
      int r = d >> 3, cd = d & 7;
      int cs = cd ^ (r & 7);
      const u16* g = Aptr + (((size_t)(m0 + r)) << 10) + kk + cs * 8;
      __builtin_amdgcn_global_load_lds((const __attribute__((address_space(1))) void*)g,
                                       (__attribute__((address_space(3))) void*)(Ad + d * 8),
                                       16, 0, 0);
    }
    #pragma unroll
    for (int i = 0; i < 4; ++i) {                  // B: 128 rows x 8 chunks
      int d = i * 256 + tid;
      int r = d >> 3, cd = d & 7;
      int cs = cd ^ (r & 7);
      const u16* g = Wb + (size_t)r * K + k0 + cs * 8;
      __builtin_amdgcn_global_load_lds((const __attribute__((address_space(1))) void*)g,
                                       (__attribute__((address_space(3))) void*)(Bd + d * 8),
                                       16, 0, 0);
    }
  };

  stage(0, 0);
  stage(1, 1);

  for (int kt = 0; kt < NT; ++kt) {
    if (kt + 2 < NT) {
      stage((kt + 2) % 3, kt + 2);
      asm volatile("s_waitcnt vmcnt(12)" ::: "memory");
    } else if (kt + 1 < NT) {
      asm volatile("s_waitcnt vmcnt(6)" ::: "memory");
    } else {
      asm volatile("s_waitcnt vmcnt(0)" ::: "memory");
    }
    __builtin_amdgcn_s_barrier();
    __builtin_amdgcn_sched_barrier(0);

    const u16* Asb = smem + (kt % 3) * 12288;
    const u16* Bsb = Asb + 4096;
    #pragma unroll
    for (int ks = 0; ks < 2; ++ks) {
      const int sw = (ks * 4 + lk) ^ (lr & 7);
      short8 a[2], b[4];
      #pragma unroll
      for (int mi = 0; mi < 2; ++mi)
        a[mi] = *reinterpret_cast<const short8*>(Asb + (wr * 32 + mi * 16 + lr) * 64 + sw * 8);
      #pragma unroll
      for (int g = 0; g < 4; ++g)
        b[g] = *reinterpret_cast<const short8*>(Bsb + (wc * 64 + g * 16 + lr) * 64 + sw * 8);
      #pragma unroll
      for (int mi = 0; mi < 2; ++mi)
        #pragma unroll
        for (int g = 0; g < 4; ++g)
          acc[mi][g] = __builtin_amdgcn_mfma_f32_16x16x32_bf16(a[mi], b[g], acc[mi][g], 0, 0, 0);
    }
    asm volatile("s_waitcnt lgkmcnt(0)" ::: "memory");
    __builtin_amdgcn_s_barrier();
    __builtin_amdgcn_sched_barrier(0);
  }
}

// ---- h0/h1 init: h = tanh(z @ to_h_W^T + to_h_b)  (grid 128: 16 bx x 8 by, N=2048)
__global__ __launch_bounds__(256, 1)
void init_gemm(const u16* __restrict__ zb, const u16* __restrict__ thwb,
               const float* __restrict__ thb, u16* __restrict__ h0, u16* __restrict__ h1) {
  __shared__ u16 smem[3 * 12288];
  const int tid  = threadIdx.x;
  const int lane = tid & 63, wave = tid >> 6;
  const int wr = wave >> 1, wc = wave & 1;
  const int lr = lane & 15, lk = lane >> 4;
  const int bx = blockIdx.x & 15, by = blockIdx.x >> 4;
  const int m0 = by * BM, n0 = bx * BN;

  f32x4 acc[2][4];
  gemm_tile<1024>(smem, zb, zb, thwb + (size_t)n0 * 1024, m0, tid, wr, wc, lr, lk, acc);

  #pragma unroll
  for (int g = 0; g < 4; ++g) {
    int n = n0 + wc * 64 + g * 16 + lr;
    float bn = thb[n];
    int lsel = n >> 10, j = n & 1023;
    u16* hb = lsel ? h1 : h0;
    #pragma unroll
    for (int mi = 0; mi < 2; ++mi)
      #pragma unroll
      for (int i = 0; i < 4; ++i) {
        int r = m0 + wr * 32 + mi * 16 + lk * 4 + i;
        hb[((size_t)r << 10) + j] = f2bf(tanhfast(acc[mi][g][i] + bn));
      }
  }
}

// ---- the whole 32-step 2-layer LSTM in ONE kernel.
// 256 blocks (1/CU, co-resident), block -> (bx 0..31, by 0..7), XCD-pinned via
// bid%8: per-XCD weight slice = 4 bx x 128 rows x 2 layers x 2048 x 2B = 4MB (L2-resident).
// c-state lives in registers. h ping-pong in global + flag semaphores per (t, by).
__global__ __launch_bounds__(256, 1)
void lstm_persistent(const u16* __restrict__ xb,
                     const u16* __restrict__ W2, const float* __restrict__ bias2,
                     u16* __restrict__ h0a, u16* __restrict__ h0c,
                     u16* __restrict__ h1a, u16* __restrict__ h1c,
                     float* __restrict__ yout, int* __restrict__ f0, int* __restrict__ f1)
{
  __shared__ u16 smem[3 * 12288];
  const int tid  = threadIdx.x;
  const int lane = tid & 63, wave = tid >> 6;
  const int wr = wave >> 1, wc = wave & 1;
  const int lr = lane & 15, lk = lane >> 4;
  const int xcd = blockIdx.x & 7, win = blockIdx.x >> 3;
  const int bx = xcd * 4 + (win >> 3);             // 0..31
  const int by = win & 7;                          // 0..7
  const int m0 = by * BM, n0 = bx * BN;

  const u16* Wl0 = W2 + (size_t)n0 * 2048;
  const u16* Wl1 = W2 + (size_t)4096 * 2048 + (size_t)n0 * 2048;
  const float b0i = bias2[n0 + wc * 64 +  0 + lr];
  const float b0f = bias2[n0 + wc * 64 + 16 + lr];
  const float b0g = bias2[n0 + wc * 64 + 32 + lr];
  const float b0o = bias2[n0 + wc * 64 + 48 + lr];
  const float b1i = bias2[4096 + n0 + wc * 64 +  0 + lr];
  const float b1f = bias2[4096 + n0 + wc * 64 + 16 + lr];
  const float b1g = bias2[4096 + n0 + wc * 64 + 32 + lr];
  const float b1o = bias2[4096 + n0 + wc * 64 + 48 + lr];
  const int j = (bx * 2 + wc) * 16 + lr;           // hidden unit

  float c0r[2][4] = {{0.f,0.f,0.f,0.f},{0.f,0.f,0.f,0.f}};
  float c1r[2][4] = {{0.f,0.f,0.f,0.f},{0.f,0.f,0.f,0.f}};
  f32x4 acc[2][4];

  for (int t = 0; t < TSTEPS; ++t) {
    const int p = t & 1;
    const u16* h0_rd = p ? h0c : h0a;
    u16*       h0_wr = p ? h0a : h0c;
    const u16* h1_rd = p ? h1c : h1a;
    u16*       h1_wr = p ? h1a : h1c;
    const u16* x     = (t == 0) ? xb : h1_rd;

    if (t > 0) wait_flag(&f1[(t - 1) * 8 + by], 32, tid);

    // ---- layer 0: gates = [x | h0_old] @ W0^T
    gemm_tile<2048>(smem, x, h0_rd, Wl0, m0, tid, wr, wc, lr, lk, acc);
    #pragma unroll
    for (int mi = 0; mi < 2; ++mi)
      #pragma unroll
      for (int i = 0; i < 4; ++i) {
        int r = m0 + wr * 32 + mi * 16 + lk * 4 + i;
        float ig = sigm(acc[mi][0][i] + b0i);
        float fg = sigm(acc[mi][1][i] + b0f);
        float gg = tanhfast(acc[mi][2][i] + b0g);
        float og = sigm(acc[mi][3][i] + b0o);
        float cn = fg * c0r[mi][i] + ig * gg;
        c0r[mi][i] = cn;
        h0_wr[((size_t)r << 10) + j] = f2bf(og * tanhfast(cn));
      }
    post_flag(&f0[t * 8 + by], tid);
    wait_flag(&f0[t * 8 + by], 32, tid);

    // ---- layer 1: gates = [h0_new | h1_old] @ W1^T
    gemm_tile<2048>(smem, h0_wr, h1_rd, Wl1, m0, tid, wr, wc, lr, lk, acc);
    float* yt = yout + ((size_t)t << 19);
    #pragma unroll
    for (int mi = 0; mi < 2; ++mi)
      #pragma unroll
      for (int i = 0; i < 4; ++i) {
        int r = m0 + wr * 32 + mi * 16 + lk * 4 + i;
        float ig = sigm(acc[mi][0][i] + b1i);
        float fg = sigm(acc[mi][1][i] + b1f);
        float gg = tanhfast(acc[mi][2][i] + b1g);
        float og = sigm(acc[mi][3][i] + b1o);
        float cn = fg * c1r[mi][i] + ig * gg;
        c1r[mi][i] = cn;
        float hn = og * tanhfast(cn);
        h1_wr[((size_t)r << 10) + j] = f2bf(hn);
        yt[((size_t)r << 10) + j] = hn;
      }
    post_flag(&f1[t * 8 + by], tid);
  }
}

extern "C" void kernel_launch(void* const* d_in, const int* in_sizes, int n_in,
                              void* d_out, int out_size, void* d_ws, size_t ws_size,
                              hipStream_t stream) {
  const float* z   = (const float*)d_in[0];
  const float* thw = (const float*)d_in[1];
  const float* thb = (const float*)d_in[2];
  const float* emb = (const float*)d_in[3];
  const float* Wih = (const float*)d_in[4];
  const float* Whh = (const float*)d_in[5];
  const float* bih = (const float*)d_in[6];
  const float* bhh = (const float*)d_in[7];
  float* out = (float*)d_out;

  char* ws = (char*)d_ws;
  size_t off = 0;
  auto carve = [&](size_t bytes) { char* p = ws + off; off += (bytes + 255) & ~(size_t)255; return p; };
  u16* W2      = (u16*)carve((size_t)NL * 4096 * 2048 * 2);  // 33.5 MB gate-interleaved
  u16* thwb    = (u16*)carve((size_t)2048 * 1024 * 2);
  u16* zb      = (u16*)carve((size_t)BSZ * HD * 2);
  u16* xb      = (u16*)carve((size_t)BSZ * HD * 2);
  u16* h0a     = (u16*)carve((size_t)BSZ * HD * 2);
  u16* h0c     = (u16*)carve((size_t)BSZ * HD * 2);
  u16* h1a     = (u16*)carve((size_t)BSZ * HD * 2);
  u16* h1c     = (u16*)carve((size_t)BSZ * HD * 2);
  float* bias2 = (float*)carve((size_t)NL * 4096 * 4);
  int* flags   = (int*)carve(2 * TSTEPS * 8 * 4);
  if (off > ws_size) return;
  int* f0 = flags;
  int* f1 = flags + TSTEPS * 8;

  pack_w2   <<<8192, 256, 0, stream>>>(Wih, Whh, W2);
  pack_thw  <<<1024, 256, 0, stream>>>(thw, thwb);
  pack_small<<< 546, 256, 0, stream>>>(z, emb, bih, bhh, zb, xb, bias2, flags);

  init_gemm<<<128, 256, 0, stream>>>(zb, thwb, thb, h0a, h1a);

  lstm_persistent<<<256, 256, 0, stream>>>(xb, W2, bias2, h0a, h0c, h1a, h1c,
                                           out, f0, f1);
}